// Round 10
// baseline (1227.144 us; speedup 1.0000x reference)
//
#include <hip/hip_runtime.h>
#include <math.h>

#define N_NODES 10000
#define N_EDGES 160000
#define ED 32
#define NBASIS 8
#define MS 16
#define MV 8
#define CS 24
#define RH 64

// ---- workspace layout (float offsets) ----
enum {
  OFS_YS    = 0,                         // [N,16]
  OFS_YSO   = OFS_YS  + N_NODES*MS,      // [N,16]
  OFS_YV    = OFS_YSO + N_NODES*MS,      // [N,8,3]
  OFS_YVO   = OFS_YV  + N_NODES*24,      // [N,8,3]
  OFS_X     = OFS_YVO + N_NODES*24,      // [N,6]
  OFS_ZS    = OFS_X   + N_NODES*6,       // [N,16]
  OFS_ZV    = OFS_ZS  + N_NODES*MS,      // [N,8,3]
  OFS_SCS   = OFS_ZV  + N_NODES*24,      // [N,24]
  OFS_SCV   = OFS_SCS + N_NODES*CS,      // [N,8,3]
  OFS_MS_   = OFS_SCV + N_NODES*24,      // [N,24]
  OFS_MV_   = OFS_MS_ + N_NODES*CS,      // [N,8,3]
  OFS_ATTRM = OFS_MV_ + N_NODES*24,      // 20 * 1408 per-attr contracted weights
  OFS_END   = OFS_ATTRM + 20*1408
};
// per-attr table sub-offsets (within 1408-float block)
#define AT_SCS 0      // [16][24]
#define AT_SCV 384    // [8][8]
#define AT_L1S 448    // [16][16]
#define AT_L1V 704    // [8][8]
#define AT_L2S 768    // [24][24]
#define AT_L2V 1344   // [8][8]

#define INV_SQRT512 0.04419417382415922f
#define INV16       0.0625f
#define INV_SQRT768 0.03608439182435161f
#define C_S 0.3826834323650898f
#define C_X 0.9238795325112867f
#define INV_SQRT8 0.35355339059327373f
#define SQRT3 1.7320508075688772f
#define SQRT8 2.8284271247461903f
#define HALF_PI 1.5707963267948966f
// out_s scale: (1/sqrt(RH)) * 1/(sqrt(MV*2)*sqrt(3)) * 1/sqrt(NUM_NEIGH)
#define SCALE_S 0.0045105181513385635f
// out_v scale: (1/sqrt(RH)) * 1/sqrt(MS*2) * 1/sqrt(NUM_NEIGH)
#define SCALE_V 0.0055242717280199025f

__device__ __forceinline__ float sigmoidf_(float v) { return 1.f / (1.f + expf(-v)); }

// ---- init: ys=0, yv = x@K, x_cur = x ----
__global__ void __launch_bounds__(256) k_init(const float* __restrict__ x_in,
                                              const float* __restrict__ K,
                                              float* __restrict__ ws) {
  int n = blockIdx.x * blockDim.x + threadIdx.x;
  if (n >= N_NODES) return;
  float xv[6];
#pragma unroll
  for (int j = 0; j < 6; j++) xv[j] = x_in[n*6 + j];
#pragma unroll
  for (int j = 0; j < 6; j++) ws[OFS_X + n*6 + j] = xv[j];
#pragma unroll
  for (int j = 0; j < MS; j++) { ws[OFS_YS + n*MS + j] = 0.f; ws[OFS_YSO + n*MS + j] = 0.f; }
#pragma unroll
  for (int k = 0; k < MV; k++)
#pragma unroll
    for (int d = 0; d < 3; d++) {
      float v = xv[d] * K[k] + xv[3+d] * K[8+k];
      ws[OFS_YV  + n*24 + k*3 + d] = v;
      ws[OFS_YVO + n*24 + k*3 + d] = v;
    }
}

// ---- per-layer: contract each weight tensor with the 20 embedding rows ----
__global__ void __launch_bounds__(256) k_attr(const float* __restrict__ emb,
                                              const float* __restrict__ sc_s,
                                              const float* __restrict__ sc_v,
                                              const float* __restrict__ l1s,
                                              const float* __restrict__ l1v,
                                              const float* __restrict__ l2s,
                                              const float* __restrict__ l2v,
                                              float* __restrict__ ws, int* __restrict__ ctr) {
  int t = blockIdx.x;
  if (t == 0 && threadIdx.x == 0) *ctr = 0;  // zero active-edge counter (runs before compact)
  const float* e = emb + t * ED;
  float* outb = ws + OFS_ATTRM + t * 1408;
  for (int j = threadIdx.x; j < 1408; j += blockDim.x) {
    float acc = 0.f;
    if (j < 384) {            // sc_s eff [16][24]
      int i2 = j / 24, o = j % 24;
      for (int q = 0; q < ED; q++) acc += e[q] * sc_s[(i2*ED + q)*24 + o];
    } else if (j < 448) {     // sc_v eff [8][8]
      int jj = j - 384; int i2 = jj / 8, o = jj % 8;
      for (int q = 0; q < ED; q++) acc += e[q] * sc_v[(i2*ED + q)*8 + o];
    } else if (j < 704) {     // lin1_s eff [16][16]
      int jj = j - 448; int i2 = jj / 16, o = jj % 16;
      for (int q = 0; q < ED; q++) acc += e[q] * l1s[(i2*ED + q)*16 + o];
    } else if (j < 768) {     // lin1_v eff [8][8]
      int jj = j - 704; int i2 = jj / 8, o = jj % 8;
      for (int q = 0; q < ED; q++) acc += e[q] * l1v[(i2*ED + q)*8 + o];
    } else if (j < 1344) {    // lin2_s eff [24][24]
      int jj = j - 768; int i2 = jj / 24, o = jj % 24;
      for (int q = 0; q < ED; q++) acc += e[q] * l2s[(i2*ED + q)*24 + o];
    } else {                  // lin2_v eff [8][8]
      int jj = j - 1344; int i2 = jj / 8, o = jj % 8;
      for (int q = 0; q < ED; q++) acc += e[q] * l2v[(i2*ED + q)*8 + o];
    }
    outb[j] = acc;
  }
}

// ---- node pre: scs, scv, zs, zv via per-attr matrices; zero m_s/m_v ----
__global__ void __launch_bounds__(256) k_node_pre(const int* __restrict__ attr,
                                                  float* __restrict__ ws) {
  int n = blockIdx.x * blockDim.x + threadIdx.x;
  if (n >= N_NODES) return;
  const float* M = ws + OFS_ATTRM + attr[n] * 1408;
  float ys[MS], yv[24];
#pragma unroll
  for (int j = 0; j < MS; j++) ys[j] = ws[OFS_YS + n*MS + j];
#pragma unroll
  for (int j = 0; j < 24; j++) yv[j] = ws[OFS_YV + n*24 + j];
  for (int o = 0; o < CS; o++) {
    float acc = 0.f;
#pragma unroll
    for (int i2 = 0; i2 < MS; i2++) acc += ys[i2] * M[AT_SCS + i2*24 + o];
    ws[OFS_SCS + n*CS + o] = acc * INV_SQRT512;
  }
  for (int o = 0; o < MS; o++) {
    float acc = 0.f;
#pragma unroll
    for (int i2 = 0; i2 < MS; i2++) acc += ys[i2] * M[AT_L1S + i2*16 + o];
    ws[OFS_ZS + n*MS + o] = acc * INV_SQRT512;
  }
  for (int o = 0; o < MV; o++) {
#pragma unroll
    for (int d = 0; d < 3; d++) {
      float a1 = 0.f, a2 = 0.f;
#pragma unroll
      for (int i2 = 0; i2 < MV; i2++) {
        float y = yv[i2*3 + d];
        a1 += y * M[AT_SCV + i2*8 + o];
        a2 += y * M[AT_L1V + i2*8 + o];
      }
      ws[OFS_SCV + n*24 + o*3 + d] = a1 * INV16;
      ws[OFS_ZV  + n*24 + o*3 + d] = a2 * INV16;
    }
  }
#pragma unroll
  for (int j = 0; j < 24; j++) { ws[OFS_MS_ + n*24 + j] = 0.f; ws[OFS_MV_ + n*24 + j] = 0.f; }
}

// ---- compact: keep edges where at least one channel has nonzero cutoff ----
__global__ void __launch_bounds__(256) k_compact(const int* __restrict__ src,
                                                 const int* __restrict__ dst,
                                                 const float* __restrict__ ws,
                                                 int* __restrict__ ctr, int* __restrict__ act) {
  int e = blockIdx.x * blockDim.x + threadIdx.x;
  if (e >= N_EDGES) return;
  const float* x = ws + OFS_X;
  int s = src[e], t = dst[e];
  float l0 = 0.f, l1 = 0.f;
#pragma unroll
  for (int d = 0; d < 3; d++) {
    float d0 = x[s*6 + d]     - x[t*6 + d];
    float d1 = x[s*6 + 3 + d] - x[t*6 + 3 + d];
    l0 += d0 * d0; l1 += d1 * d1;
  }
  if (l0 < 4.f || l1 < 4.f) {
    int i = atomicAdd(ctr, 1);
    act[i] = e;
  }
}

// ---- edge kernel v5: v4 + 2 edges per lane ----
// R9: VALUBusy 23%, scalar-latency-bound (~1200cy/iter s_load chain vs ~810cy
// VALU). Each wave-shared w2 value (SGPR) now feeds TWO edges' FMA chains:
// VALU/iter ~1650cy > latency ~1200cy -> VALU-bound. Total scalar stream
// halves (half the waves, same per-wave stream). Watch VGPR (~140 expected):
// spill signature = FETCH explosion (R6 lesson).
template<bool HAS_ZS>
__global__ void __launch_bounds__(256) k_edge5(const int* __restrict__ src,
                                               const int* __restrict__ dst,
                                               const float* __restrict__ w1,
                                               const float* __restrict__ w2,
                                               float* __restrict__ ws,
                                               const int* __restrict__ ctr,
                                               const int* __restrict__ act) {
  __shared__ float redA[HAS_ZS ? 1 : 3][64][49];   // os partials, 2 edges (odd stride)
  __shared__ float redB[HAS_ZS ? 64 : 1][33];      // tA partials, 2 edges (odd stride)

  int lane = threadIdx.x & 63;
  int wv   = __builtin_amdgcn_readfirstlane(threadIdx.x >> 6);  // provably scalar
  int nact = *ctr;
  int tile = blockIdx.x * 128;
  if (tile >= nact) return;                 // block-uniform early out
  int idx0 = tile + lane, idx1 = tile + 64 + lane;
  bool alive[2] = { idx0 < nact, idx1 < nact };
  int e0 = act[alive[0] ? idx0 : 0];
  int e1 = act[alive[1] ? idx1 : 0];
  int sn[2] = { src[e0], src[e1] };
  int dn[2] = { dst[e0], dst[e1] };
  const float* x = ws + OFS_X;

  // ---- geometry for both edges ----
  float feat[2][16], eattr[2][2][3];
#pragma unroll
  for (int u = 0; u < 2; u++) {
#pragma unroll
    for (int c = 0; c < 2; c++) {
      float ev[3]; float acc = 0.f;
#pragma unroll
      for (int d = 0; d < 3; d++) {
        float v = x[sn[u]*6 + c*3 + d] - x[dn[u]*6 + c*3 + d];
        ev[d] = v; acc += v * v;
      }
      float l = sqrtf(acc);
      float tt = HALF_PI * l;
      float s1 = sinf(tt), c1 = cosf(tt);
      float cut = (l > 2.f) ? 0.f : ((l < 1.f) ? 1.f : s1 * s1);
      float invl = 1.f / l;
      float fs = SQRT8 * invl;
      float snm1 = 0.f, snv = s1, twoc1 = 2.f * c1;
#pragma unroll
      for (int b = 0; b < NBASIS; b++) {
        feat[u][c*NBASIS + b] = snv * fs;
        float nx = twoc1 * snv - snm1;
        snm1 = snv; snv = nx;
      }
      float es = cut * SQRT3 * invl;
#pragma unroll
      for (int d = 0; d < 3; d++) eattr[u][c][d] = es * ev[d];
    }
  }

  const int role  = HAS_ZS ? (wv >> 1) : 0;                // scalar: 0 = os_, 1 = tA
  const int rbase = HAS_ZS ? ((wv & 1) * 32) : (wv * 16);  // scalar
  const int rspan = HAS_ZS ? 32 : 16;

  // role-dependent input vectors (sE for role 0, zss for role 1)
  float inp[2][16];
  if (role == 0) {
#pragma unroll
    for (int u = 0; u < 2; u++)
#pragma unroll
      for (int i2 = 0; i2 < MV; i2++) {
        float z0 = ws[OFS_ZV + sn[u]*24 + i2*3 + 0];
        float z1 = ws[OFS_ZV + sn[u]*24 + i2*3 + 1];
        float z2 = ws[OFS_ZV + sn[u]*24 + i2*3 + 2];
#pragma unroll
        for (int c = 0; c < 2; c++)
          inp[u][i2*2 + c] = z0*eattr[u][c][0] + z1*eattr[u][c][1] + z2*eattr[u][c][2];
      }
  } else {
#pragma unroll
    for (int u = 0; u < 2; u++)
#pragma unroll
      for (int j = 0; j < MS; j++) inp[u][j] = ws[OFS_ZS + sn[u]*MS + j];
  }

  float accv[2][24];
#pragma unroll
  for (int u = 0; u < 2; u++)
#pragma unroll
    for (int j = 0; j < 24; j++) accv[u][j] = 0.f;

  if (role == 0) {
#pragma unroll 1
    for (int rr = 0; rr < rspan; rr++) {
      int r = rbase + rr;                   // scalar -> s_load operands
      float h0 = 0.f, h1 = 0.f;
#pragma unroll
      for (int f = 0; f < 16; f++) {
        float wr = w1[f*RH + r];            // scalar
        h0 += feat[0][f] * wr; h1 += feat[1][f] * wr;
      }
      h0 *= 0.25f; h1 *= 0.25f;
      float hr0 = h0 * sigmoidf_(h0), hr1 = h1 * sigmoidf_(h1);
      const float* row = w2 + r * 640;      // scalar base
#pragma unroll
      for (int o = 0; o < CS; o++) {
        float a0 = 0.f, a1 = 0.f;
#pragma unroll
        for (int p = 0; p < 16; p++) {
          float wvv = row[256 + p*24 + o];  // scalar, shared by both edges
          a0 += inp[0][p] * wvv; a1 += inp[1][p] * wvv;
        }
        accv[0][o] += hr0 * a0; accv[1][o] += hr1 * a1;
      }
    }
  } else {
#pragma unroll 1
    for (int rr = 0; rr < 32; rr++) {
      int r = rbase + rr;
      float h0 = 0.f, h1 = 0.f;
#pragma unroll
      for (int f = 0; f < 16; f++) {
        float wr = w1[f*RH + r];
        h0 += feat[0][f] * wr; h1 += feat[1][f] * wr;
      }
      h0 *= 0.25f; h1 *= 0.25f;
      float hr0 = h0 * sigmoidf_(h0), hr1 = h1 * sigmoidf_(h1);
      const float* row = w2 + r * 640;
#pragma unroll
      for (int co = 0; co < 16; co++) {     // co = c*8+o
        float a0 = 0.f, a1 = 0.f;
#pragma unroll
        for (int i2 = 0; i2 < MS; i2++) {
          float wvv = row[i2*16 + co];      // scalar, shared
          a0 += inp[0][i2] * wvv; a1 += inp[1][i2] * wvv;
        }
        accv[0][co] += hr0 * a0; accv[1][co] += hr1 * a1;
      }
    }
  }

  // ---- cross-wave reduce + scatter ----
  if (HAS_ZS) {
    if (wv == 1) {
#pragma unroll
      for (int u = 0; u < 2; u++)
#pragma unroll
        for (int j = 0; j < 24; j++) redA[0][lane][u*24 + j] = accv[u][j];
    } else if (wv == 3) {
#pragma unroll
      for (int u = 0; u < 2; u++)
#pragma unroll
        for (int j = 0; j < 16; j++) redB[lane][u*16 + j] = accv[u][j];
    }
    __syncthreads();
    if (wv == 0) {
#pragma unroll
      for (int u = 0; u < 2; u++)
        if (alive[u]) {
#pragma unroll
          for (int o = 0; o < 24; o++) {
            float v = accv[u][o] + redA[0][lane][u*24 + o];
            atomicAdd(&ws[OFS_MS_ + dn[u]*24 + o], v * SCALE_S);
          }
        }
    } else if (wv == 2) {
#pragma unroll
      for (int u = 0; u < 2; u++)
        if (alive[u]) {
          float TA[16];
#pragma unroll
          for (int j = 0; j < 16; j++) TA[j] = accv[u][j] + redB[lane][u*16 + j];
#pragma unroll
          for (int o = 0; o < MV; o++)
#pragma unroll
            for (int d = 0; d < 3; d++) {
              float ov = eattr[u][0][d] * TA[o] + eattr[u][1][d] * TA[8 + o];
              atomicAdd(&ws[OFS_MV_ + dn[u]*24 + o*3 + d], ov * SCALE_V);
            }
        }
    }
  } else {
    if (wv > 0) {
#pragma unroll
      for (int u = 0; u < 2; u++)
#pragma unroll
        for (int j = 0; j < 24; j++) redA[wv-1][lane][u*24 + j] = accv[u][j];
    }
    __syncthreads();
    if (wv == 0) {
#pragma unroll
      for (int u = 0; u < 2; u++)
        if (alive[u]) {
#pragma unroll
          for (int o = 0; o < 24; o++) {
            float v = accv[u][o] + redA[0][lane][u*24 + o]
                    + redA[1][lane][u*24 + o] + redA[2][lane][u*24 + o];
            atomicAdd(&ws[OFS_MS_ + dn[u]*24 + o], v * SCALE_S);
          }
        }
    }
  }
}

// ---- node post: lin2, gate, self-interaction, leapfrog, project x ----
__global__ void __launch_bounds__(256) k_node_post(const int* __restrict__ attr,
                                                   const float* __restrict__ si_s,
                                                   const float* __restrict__ si_v,
                                                   const float* __restrict__ K,
                                                   const float* __restrict__ h_arr,
                                                   const float* __restrict__ mix_arr,
                                                   int layer, float* __restrict__ ws) {
  int n = blockIdx.x * blockDim.x + threadIdx.x;
  if (n >= N_NODES) return;
  const float* M = ws + OFS_ATTRM + attr[n] * 1408;

  float msv[24], mvv[24];
#pragma unroll
  for (int j = 0; j < 24; j++) { msv[j] = ws[OFS_MS_ + n*24 + j]; mvv[j] = ws[OFS_MV_ + n*24 + j]; }

  float cs_out[24], cv_out[24];
  for (int o = 0; o < CS; o++) {
    float acc = 0.f;
#pragma unroll
    for (int i2 = 0; i2 < CS; i2++) acc += msv[i2] * M[AT_L2S + i2*24 + o];
    cs_out[o] = C_S * ws[OFS_SCS + n*CS + o] + C_X * acc * INV_SQRT768;
  }
  for (int o = 0; o < MV; o++) {
#pragma unroll
    for (int d = 0; d < 3; d++) {
      float acc = 0.f;
#pragma unroll
      for (int i2 = 0; i2 < MV; i2++) acc += mvv[i2*3 + d] * M[AT_L2V + i2*8 + o];
      cv_out[o*3 + d] = C_S * ws[OFS_SCV + n*24 + o*3 + d] + C_X * acc * INV16;
    }
  }

  float ys[MS], yso[MS], yv[24], yvo[24];
#pragma unroll
  for (int j = 0; j < MS; j++) { ys[j] = ws[OFS_YS + n*MS + j]; yso[j] = ws[OFS_YSO + n*MS + j]; }
#pragma unroll
  for (int j = 0; j < 24; j++) { yv[j] = ws[OFS_YV + n*24 + j]; yvo[j] = ws[OFS_YVO + n*24 + j]; }

  float hv = h_arr[layer];
  float dt = fminf(fmaxf(hv*hv, 1e-4f), 0.1f);
  float mxv = mix_arr[layer];
  float m = fminf(mxv*mxv, 1.f);

#pragma unroll
  for (int o = 0; o < MS; o++) {
    float g = cs_out[o] * sigmoidf_(cs_out[o]);
    float si = 0.f;
#pragma unroll
    for (int i2 = 0; i2 < MS; i2++) si += ys[i2] * si_s[i2*16 + o];
    si *= 0.25f;
    float dsv = m * g + (1.f - m) * si;
    float ysn = 2.f*ys[o] - yso[o] + dt * dsv;
    ws[OFS_YSO + n*MS + o] = ys[o];
    ws[OFS_YS  + n*MS + o] = ysn;
  }
  float yvn[24];
#pragma unroll
  for (int o = 0; o < MV; o++) {
    float gate = sigmoidf_(cs_out[MS + o]);
#pragma unroll
    for (int d = 0; d < 3; d++) {
      float si = 0.f;
#pragma unroll
      for (int i2 = 0; i2 < MV; i2++) si += yv[i2*3 + d] * si_v[i2*8 + o];
      si *= INV_SQRT8;
      float dv = m * gate * cv_out[o*3 + d] + (1.f - m) * si;
      float v = 2.f*yv[o*3 + d] - yvo[o*3 + d] + dt * dv;
      yvn[o*3 + d] = v;
      ws[OFS_YVO + n*24 + o*3 + d] = yv[o*3 + d];
      ws[OFS_YV  + n*24 + o*3 + d] = v;
    }
  }
#pragma unroll
  for (int c = 0; c < 2; c++)
#pragma unroll
    for (int d = 0; d < 3; d++) {
      float acc = 0.f;
#pragma unroll
      for (int k = 0; k < MV; k++) acc += yvn[k*3 + d] * K[c*8 + k];
      ws[OFS_X + n*6 + c*3 + d] = acc;
    }
}

// ---- finalize: copy x to d_out + tail scalars ----
__global__ void __launch_bounds__(256) k_final(const float* __restrict__ ws,
                                               float* __restrict__ out) {
  int i = blockIdx.x * blockDim.x + threadIdx.x;
  if (i < N_NODES*6) out[i] = ws[OFS_X + i];
  if (i == 0) { out[N_NODES*6] = -1.f; out[N_NODES*6 + 1] = -1.f; out[N_NODES*6 + 2] = 0.f; }
}

extern "C" void kernel_launch(void* const* d_in, const int* in_sizes, int n_in,
                              void* d_out, int out_size, void* d_ws, size_t ws_size,
                              hipStream_t stream) {
  const float* x_in  = (const float*)d_in[0];
  const int*   attr  = (const int*)  d_in[2];
  const int*   esrc  = (const int*)  d_in[3];
  const int*   edst  = (const int*)  d_in[4];
  const float* emb   = (const float*)d_in[5];
  const float* Kp    = (const float*)d_in[6];
  const float* hp    = (const float*)d_in[7];
  const float* mixp  = (const float*)d_in[8];
  const float* sc_s  = (const float*)d_in[9];
  const float* sc_v  = (const float*)d_in[10];
  const float* l1s   = (const float*)d_in[11];
  const float* l1v   = (const float*)d_in[12];
  const float* w1    = (const float*)d_in[13];
  const float* w2    = (const float*)d_in[14];
  const float* l2s   = (const float*)d_in[15];
  const float* l2v   = (const float*)d_in[16];
  const float* si_s  = (const float*)d_in[17];
  const float* si_v  = (const float*)d_in[18];

  float* ws = (float*)d_ws;
  int* ibase = (int*)(ws + OFS_END);
  int* ctr = ibase;
  int* act = ibase + 1;
  float* out = (float*)d_out;

  k_init<<<(N_NODES + 255)/256, 256, 0, stream>>>(x_in, Kp, ws);
  for (int i = 0; i < 2; i++) {
    k_attr<<<20, 256, 0, stream>>>(emb,
        sc_s + (size_t)i*MS*ED*CS, sc_v + (size_t)i*MV*ED*MV,
        l1s + (size_t)i*MS*ED*MS, l1v + (size_t)i*MV*ED*MV,
        l2s + (size_t)i*CS*ED*CS, l2v + (size_t)i*MV*ED*MV, ws, ctr);
    k_node_pre<<<(N_NODES + 255)/256, 256, 0, stream>>>(attr, ws);
    k_compact<<<(N_EDGES + 255)/256, 256, 0, stream>>>(esrc, edst, ws, ctr, act);
    if (i == 0)
      k_edge5<false><<<(N_EDGES + 127)/128, 256, 0, stream>>>(esrc, edst,
          w1 + (size_t)i*2*NBASIS*RH, w2 + (size_t)i*RH*640, ws, ctr, act);
    else
      k_edge5<true><<<(N_EDGES + 127)/128, 256, 0, stream>>>(esrc, edst,
          w1 + (size_t)i*2*NBASIS*RH, w2 + (size_t)i*RH*640, ws, ctr, act);
    k_node_post<<<(N_NODES + 255)/256, 256, 0, stream>>>(attr,
        si_s + (size_t)i*MS*MS, si_v + (size_t)i*MV*MV, Kp, hp, mixp, i, ws);
  }
  k_final<<<(N_NODES*6 + 2 + 255)/256, 256, 0, stream>>>(ws, out);
}

// Round 14
// 769.360 us; speedup vs baseline: 1.5950x; 1.5950x over previous
//
#include <hip/hip_runtime.h>
#include <math.h>

#define N_NODES 10000
#define N_EDGES 160000
#define ED 32
#define NBASIS 8
#define MS 16
#define MV 8
#define CS 24
#define RH 64

// ---- workspace layout (float offsets) ----
enum {
  OFS_YS    = 0,                         // [N,16]
  OFS_YSO   = OFS_YS  + N_NODES*MS,      // [N,16]
  OFS_YV    = OFS_YSO + N_NODES*MS,      // [N,8,3]
  OFS_YVO   = OFS_YV  + N_NODES*24,      // [N,8,3]
  OFS_X     = OFS_YVO + N_NODES*24,      // [N,6]
  OFS_ZS    = OFS_X   + N_NODES*6,       // [N,16]
  OFS_ZV    = OFS_ZS  + N_NODES*MS,      // [N,8,3]
  OFS_SCS   = OFS_ZV  + N_NODES*24,      // [N,24]
  OFS_SCV   = OFS_SCS + N_NODES*CS,      // [N,8,3]
  OFS_MS_   = OFS_SCV + N_NODES*24,      // [N,24]
  OFS_MV_   = OFS_MS_ + N_NODES*CS,      // [N,8,3]
  OFS_ATTRM = OFS_MV_ + N_NODES*24,      // 20 * 1408 per-attr contracted weights
  OFS_END   = OFS_ATTRM + 20*1408
};
// int area (in 4B units, offset from ws float base): ctr, deg, off, cur, eorder, act
enum {
  IOF_CTR    = OFS_END,
  IOF_DEG    = IOF_CTR + 4,              // [10000]
  IOF_OFF    = IOF_DEG + N_NODES,        // [10000]
  IOF_CUR    = IOF_OFF + N_NODES,        // [10000]
  IOF_EORD   = IOF_CUR + N_NODES,        // [160000]
  IOF_ACT    = IOF_EORD + N_EDGES,       // [160000]
  OFS_EDENSE = IOF_ACT + N_EDGES,        // [160000][48] floats (~30.7 MB)
  OFS_TOTAL  = OFS_EDENSE + N_EDGES*48
};
// per-attr table sub-offsets (within 1408-float block)
#define AT_SCS 0      // [16][24]
#define AT_SCV 384    // [8][8]
#define AT_L1S 448    // [16][16]
#define AT_L1V 704    // [8][8]
#define AT_L2S 768    // [24][24]
#define AT_L2V 1344   // [8][8]

#define INV_SQRT512 0.04419417382415922f
#define INV16       0.0625f
#define INV_SQRT768 0.03608439182435161f
#define C_S 0.3826834323650898f
#define C_X 0.9238795325112867f
#define INV_SQRT8 0.35355339059327373f
#define SQRT3 1.7320508075688772f
#define SQRT8 2.8284271247461903f
#define HALF_PI 1.5707963267948966f
// out_s scale: (1/sqrt(RH)) * 1/(sqrt(MV*2)*sqrt(3)) * 1/sqrt(NUM_NEIGH)
#define SCALE_S 0.0045105181513385635f
// out_v scale: (1/sqrt(RH)) * 1/sqrt(MS*2) * 1/sqrt(NUM_NEIGH)
#define SCALE_V 0.0055242717280199025f

__device__ __forceinline__ float sigmoidf_(float v) { return 1.f / (1.f + expf(-v)); }

// ---- init: ys=0, yv = x@K, x_cur = x ----
__global__ void __launch_bounds__(256) k_init(const float* __restrict__ x_in,
                                              const float* __restrict__ K,
                                              float* __restrict__ ws) {
  int n = blockIdx.x * blockDim.x + threadIdx.x;
  if (n >= N_NODES) return;
  float xv[6];
#pragma unroll
  for (int j = 0; j < 6; j++) xv[j] = x_in[n*6 + j];
#pragma unroll
  for (int j = 0; j < 6; j++) ws[OFS_X + n*6 + j] = xv[j];
#pragma unroll
  for (int j = 0; j < MS; j++) { ws[OFS_YS + n*MS + j] = 0.f; ws[OFS_YSO + n*MS + j] = 0.f; }
#pragma unroll
  for (int k = 0; k < MV; k++)
#pragma unroll
    for (int d = 0; d < 3; d++) {
      float v = xv[d] * K[k] + xv[3+d] * K[8+k];
      ws[OFS_YV  + n*24 + k*3 + d] = v;
      ws[OFS_YVO + n*24 + k*3 + d] = v;
    }
}

// ---- per-layer: contract weights with 20 emb rows; zero ctr + deg ----
__global__ void __launch_bounds__(256) k_attr(const float* __restrict__ emb,
                                              const float* __restrict__ sc_s,
                                              const float* __restrict__ sc_v,
                                              const float* __restrict__ l1s,
                                              const float* __restrict__ l1v,
                                              const float* __restrict__ l2s,
                                              const float* __restrict__ l2v,
                                              float* __restrict__ ws,
                                              int* __restrict__ ctr, int* __restrict__ deg) {
  int t = blockIdx.x;
  if (t == 0 && threadIdx.x == 0) *ctr = 0;
  for (int j = threadIdx.x + t*256; j < N_NODES; j += 20*256) deg[j] = 0;
  const float* e = emb + t * ED;
  float* outb = ws + OFS_ATTRM + t * 1408;
  for (int j = threadIdx.x; j < 1408; j += blockDim.x) {
    float acc = 0.f;
    if (j < 384) {            // sc_s eff [16][24]
      int i2 = j / 24, o = j % 24;
      for (int q = 0; q < ED; q++) acc += e[q] * sc_s[(i2*ED + q)*24 + o];
    } else if (j < 448) {     // sc_v eff [8][8]
      int jj = j - 384; int i2 = jj / 8, o = jj % 8;
      for (int q = 0; q < ED; q++) acc += e[q] * sc_v[(i2*ED + q)*8 + o];
    } else if (j < 704) {     // lin1_s eff [16][16]
      int jj = j - 448; int i2 = jj / 16, o = jj % 16;
      for (int q = 0; q < ED; q++) acc += e[q] * l1s[(i2*ED + q)*16 + o];
    } else if (j < 768) {     // lin1_v eff [8][8]
      int jj = j - 704; int i2 = jj / 8, o = jj % 8;
      for (int q = 0; q < ED; q++) acc += e[q] * l1v[(i2*ED + q)*8 + o];
    } else if (j < 1344) {    // lin2_s eff [24][24]
      int jj = j - 768; int i2 = jj / 24, o = jj % 24;
      for (int q = 0; q < ED; q++) acc += e[q] * l2s[(i2*ED + q)*24 + o];
    } else {                  // lin2_v eff [8][8]
      int jj = j - 1344; int i2 = jj / 8, o = jj % 8;
      for (int q = 0; q < ED; q++) acc += e[q] * l2v[(i2*ED + q)*8 + o];
    }
    outb[j] = acc;
  }
}

// ---- node pre: scs, scv, zs, zv (m_s/m_v now fully written by k_gather) ----
__global__ void __launch_bounds__(256) k_node_pre(const int* __restrict__ attr,
                                                  float* __restrict__ ws) {
  int n = blockIdx.x * blockDim.x + threadIdx.x;
  if (n >= N_NODES) return;
  const float* M = ws + OFS_ATTRM + attr[n] * 1408;
  float ys[MS], yv[24];
#pragma unroll
  for (int j = 0; j < MS; j++) ys[j] = ws[OFS_YS + n*MS + j];
#pragma unroll
  for (int j = 0; j < 24; j++) yv[j] = ws[OFS_YV + n*24 + j];
  for (int o = 0; o < CS; o++) {
    float acc = 0.f;
#pragma unroll
    for (int i2 = 0; i2 < MS; i2++) acc += ys[i2] * M[AT_SCS + i2*24 + o];
    ws[OFS_SCS + n*CS + o] = acc * INV_SQRT512;
  }
  for (int o = 0; o < MS; o++) {
    float acc = 0.f;
#pragma unroll
    for (int i2 = 0; i2 < MS; i2++) acc += ys[i2] * M[AT_L1S + i2*16 + o];
    ws[OFS_ZS + n*MS + o] = acc * INV_SQRT512;
  }
  for (int o = 0; o < MV; o++) {
#pragma unroll
    for (int d = 0; d < 3; d++) {
      float a1 = 0.f, a2 = 0.f;
#pragma unroll
      for (int i2 = 0; i2 < MV; i2++) {
        float y = yv[i2*3 + d];
        a1 += y * M[AT_SCV + i2*8 + o];
        a2 += y * M[AT_L1V + i2*8 + o];
      }
      ws[OFS_SCV + n*24 + o*3 + d] = a1 * INV16;
      ws[OFS_ZV  + n*24 + o*3 + d] = a2 * INV16;
    }
  }
}

// ---- compact + degree histogram ----
__global__ void __launch_bounds__(256) k_compact(const int* __restrict__ src,
                                                 const int* __restrict__ dst,
                                                 const float* __restrict__ ws,
                                                 int* __restrict__ ctr, int* __restrict__ act,
                                                 int* __restrict__ deg) {
  int e = blockIdx.x * blockDim.x + threadIdx.x;
  if (e >= N_EDGES) return;
  const float* x = ws + OFS_X;
  int s = src[e], t = dst[e];
  float l0 = 0.f, l1 = 0.f;
#pragma unroll
  for (int d = 0; d < 3; d++) {
    float d0 = x[s*6 + d]     - x[t*6 + d];
    float d1 = x[s*6 + 3 + d] - x[t*6 + 3 + d];
    l0 += d0 * d0; l1 += d1 * d1;
  }
  if (l0 < 4.f || l1 < 4.f) {
    int i = atomicAdd(ctr, 1);
    act[i] = e;
    atomicAdd(&deg[t], 1);
  }
}

// ---- one-block prefix sum over deg[10000] -> off, cur ----
__global__ void __launch_bounds__(256) k_scan(const int* __restrict__ deg,
                                              int* __restrict__ off, int* __restrict__ cur) {
  __shared__ int part[256];
  int t = threadIdx.x;
  int base = t * 40;
  int s = 0;
  if (t < 250)
    for (int j = 0; j < 40; j++) s += deg[base + j];
  part[t] = s;
  __syncthreads();
  for (int st = 1; st < 256; st <<= 1) {
    int v = (t >= st) ? part[t - st] : 0;
    __syncthreads();
    part[t] += v;
    __syncthreads();
  }
  int run = (t > 0) ? part[t - 1] : 0;
  if (t < 250)
    for (int j = 0; j < 40; j++) {
      int idx = base + j;
      off[idx] = run; cur[idx] = run;
      run += deg[idx];
    }
}

// ---- scatter: eorder[slot] = compacted position, grouped by dst ----
__global__ void __launch_bounds__(256) k_scatter(const int* __restrict__ act,
                                                 const int* __restrict__ dst,
                                                 const int* __restrict__ ctr,
                                                 int* __restrict__ cur,
                                                 int* __restrict__ eorder) {
  int i = blockIdx.x * blockDim.x + threadIdx.x;
  if (i >= *ctr) return;
  int e = act[i];
  int slot = atomicAdd(&cur[dst[e]], 1);
  eorder[slot] = i;
}

// ---- edge kernel v6: identical to v4 except atomics -> dense stores ----
// R10 A/B isolated the ~440us floor as atomic-throughput (5.1M fire-and-forget
// fp32 atomics/dispatch; time invariant to ILP/waves, WRITE ~ atomic count).
// Here wave 0 stores os*SCALE_S to edense[idx][0..24), wave 2 stores
// ov*SCALE_V to edense[idx][24..48); k_gather sums rows per dst node.
template<bool HAS_ZS>
__global__ void __launch_bounds__(256) k_edge6(const int* __restrict__ src,
                                               const int* __restrict__ dst,
                                               const float* __restrict__ w1,
                                               const float* __restrict__ w2,
                                               float* __restrict__ ws,
                                               const int* __restrict__ ctr,
                                               const int* __restrict__ act) {
  __shared__ float redA[HAS_ZS ? 1 : 3][64][25];   // os partials (odd stride)
  __shared__ float redB[HAS_ZS ? 64 : 1][17];      // tA partials (odd stride)

  int lane = threadIdx.x & 63;
  int wv   = __builtin_amdgcn_readfirstlane(threadIdx.x >> 6);  // provably scalar (R9 win)
  int nact = *ctr;
  int idx  = blockIdx.x * 64 + lane;
  if (blockIdx.x * 64 >= nact) return;      // block-uniform early out
  bool alive = idx < nact;
  int e = act[alive ? idx : 0];
  int s = src[e], dd = dst[e];
  const float* x = ws + OFS_X;
  float* edense = ws + OFS_EDENSE;

  // ---- geometry (duplicated per wave) ----
  float ev[2][3], ln[2];
#pragma unroll
  for (int c = 0; c < 2; c++) {
    float acc = 0.f;
#pragma unroll
    for (int d = 0; d < 3; d++) {
      float v = x[s*6 + c*3 + d] - x[dd*6 + c*3 + d];
      ev[c][d] = v; acc += v * v;
    }
    ln[c] = sqrtf(acc);
  }

  float feat[16], eattr[2][3];
#pragma unroll
  for (int c = 0; c < 2; c++) {
    float l = ln[c];
    float tt = HALF_PI * l;
    float s1 = sinf(tt), c1 = cosf(tt);
    float cut = (l > 2.f) ? 0.f : ((l < 1.f) ? 1.f : s1 * s1);
    float invl = 1.f / l;
    float fs = SQRT8 * invl;
    float snm1 = 0.f, sn = s1, twoc1 = 2.f * c1;
#pragma unroll
    for (int b = 0; b < NBASIS; b++) {
      feat[c*NBASIS + b] = sn * fs;
      float nx = twoc1 * sn - snm1;
      snm1 = sn; sn = nx;
    }
    float es = cut * SQRT3 * invl;
#pragma unroll
    for (int d = 0; d < 3; d++) eattr[c][d] = es * ev[c][d];
  }

  const int role  = HAS_ZS ? (wv >> 1) : 0;                // scalar: 0 = os_, 1 = tA
  const int rbase = HAS_ZS ? ((wv & 1) * 32) : (wv * 16);  // scalar
  const int rspan = HAS_ZS ? 32 : 16;

  float inp[16];
  if (role == 0) {
#pragma unroll
    for (int i2 = 0; i2 < MV; i2++) {
      float z0 = ws[OFS_ZV + s*24 + i2*3 + 0];
      float z1 = ws[OFS_ZV + s*24 + i2*3 + 1];
      float z2 = ws[OFS_ZV + s*24 + i2*3 + 2];
#pragma unroll
      for (int c = 0; c < 2; c++)
        inp[i2*2 + c] = z0*eattr[c][0] + z1*eattr[c][1] + z2*eattr[c][2];
    }
  } else {
#pragma unroll
    for (int j = 0; j < MS; j++) inp[j] = ws[OFS_ZS + s*MS + j];
  }

  float accv[24];
#pragma unroll
  for (int j = 0; j < 24; j++) accv[j] = 0.f;

  if (role == 0) {
#pragma unroll 1
    for (int rr = 0; rr < rspan; rr++) {
      int r = rbase + rr;                   // scalar -> s_load operands
      float h = 0.f;
#pragma unroll
      for (int f = 0; f < 16; f++) h += feat[f] * w1[f*RH + r];
      h *= 0.25f;
      float hr = h * sigmoidf_(h);
      const float* row = w2 + r * 640;      // scalar base pointer
#pragma unroll
      for (int o = 0; o < CS; o++) {
        float acc = 0.f;
#pragma unroll
        for (int p = 0; p < 16; p++) acc += inp[p] * row[256 + p*24 + o];
        accv[o] += hr * acc;
      }
    }
  } else {
#pragma unroll 1
    for (int rr = 0; rr < 32; rr++) {
      int r = rbase + rr;
      float h = 0.f;
#pragma unroll
      for (int f = 0; f < 16; f++) h += feat[f] * w1[f*RH + r];
      h *= 0.25f;
      float hr = h * sigmoidf_(h);
      const float* row = w2 + r * 640;
#pragma unroll
      for (int co = 0; co < 16; co++) {     // co = c*8+o
        float acc = 0.f;
#pragma unroll
        for (int i2 = 0; i2 < MS; i2++) acc += inp[i2] * row[i2*16 + co];
        accv[co] += hr * acc;
      }
    }
  }

  // ---- cross-wave reduce + dense store (NO atomics) ----
  if (HAS_ZS) {
    if (wv == 1) {
#pragma unroll
      for (int j = 0; j < 24; j++) redA[0][lane][j] = accv[j];
    } else if (wv == 3) {
#pragma unroll
      for (int j = 0; j < 16; j++) redB[lane][j] = accv[j];
    }
    __syncthreads();
    if (wv == 0 && alive) {
#pragma unroll
      for (int o = 0; o < 24; o++) {
        float v = accv[o] + redA[0][lane][o];
        edense[(size_t)idx*48 + o] = v * SCALE_S;
      }
    } else if (wv == 2 && alive) {
      float TA[16];
#pragma unroll
      for (int j = 0; j < 16; j++) TA[j] = accv[j] + redB[lane][j];
#pragma unroll
      for (int o = 0; o < MV; o++)
#pragma unroll
        for (int d = 0; d < 3; d++) {
          float ov = eattr[0][d] * TA[o] + eattr[1][d] * TA[8 + o];
          edense[(size_t)idx*48 + 24 + o*3 + d] = ov * SCALE_V;
        }
    }
  } else {
    if (wv > 0) {
#pragma unroll
      for (int j = 0; j < 24; j++) redA[wv-1][lane][j] = accv[j];
    }
    __syncthreads();
    if (wv == 0 && alive) {
#pragma unroll
      for (int o = 0; o < 24; o++) {
        float v = accv[o] + redA[0][lane][o] + redA[1][lane][o] + redA[2][lane][o];
        edense[(size_t)idx*48 + o] = v * SCALE_S;
      }
    }
  }
}

// ---- gather: m_s/m_v[n] = sum of this node's edge rows ----
template<bool HAS_V>
__global__ void __launch_bounds__(256) k_gather(const int* __restrict__ off,
                                                const int* __restrict__ deg,
                                                const int* __restrict__ eorder,
                                                float* __restrict__ ws) {
  int gid = blockIdx.x * blockDim.x + threadIdx.x;
  constexpr int W = HAS_V ? 48 : 24;
  if (gid >= N_NODES * W) return;
  int n = gid / W, c = gid % W;
  int o = off[n], cnt = deg[n];
  const float* edense = ws + OFS_EDENSE;
  float acc = 0.f;
  for (int j = 0; j < cnt; j++)
    acc += edense[(size_t)eorder[o + j]*48 + c];
  if (c < 24) ws[OFS_MS_ + n*24 + c] = acc;
  else        ws[OFS_MV_ + n*24 + (c - 24)] = acc;
  if (!HAS_V) ws[OFS_MV_ + n*24 + c] = 0.f;   // layer 0: m_v == 0
}

// ---- node post: lin2, gate, self-interaction, leapfrog, project x ----
__global__ void __launch_bounds__(256) k_node_post(const int* __restrict__ attr,
                                                   const float* __restrict__ si_s,
                                                   const float* __restrict__ si_v,
                                                   const float* __restrict__ K,
                                                   const float* __restrict__ h_arr,
                                                   const float* __restrict__ mix_arr,
                                                   int layer, float* __restrict__ ws) {
  int n = blockIdx.x * blockDim.x + threadIdx.x;
  if (n >= N_NODES) return;
  const float* M = ws + OFS_ATTRM + attr[n] * 1408;

  float msv[24], mvv[24];
#pragma unroll
  for (int j = 0; j < 24; j++) { msv[j] = ws[OFS_MS_ + n*24 + j]; mvv[j] = ws[OFS_MV_ + n*24 + j]; }

  float cs_out[24], cv_out[24];
  for (int o = 0; o < CS; o++) {
    float acc = 0.f;
#pragma unroll
    for (int i2 = 0; i2 < CS; i2++) acc += msv[i2] * M[AT_L2S + i2*24 + o];
    cs_out[o] = C_S * ws[OFS_SCS + n*CS + o] + C_X * acc * INV_SQRT768;
  }
  for (int o = 0; o < MV; o++) {
#pragma unroll
    for (int d = 0; d < 3; d++) {
      float acc = 0.f;
#pragma unroll
      for (int i2 = 0; i2 < MV; i2++) acc += mvv[i2*3 + d] * M[AT_L2V + i2*8 + o];
      cv_out[o*3 + d] = C_S * ws[OFS_SCV + n*24 + o*3 + d] + C_X * acc * INV16;
    }
  }

  float ys[MS], yso[MS], yv[24], yvo[24];
#pragma unroll
  for (int j = 0; j < MS; j++) { ys[j] = ws[OFS_YS + n*MS + j]; yso[j] = ws[OFS_YSO + n*MS + j]; }
#pragma unroll
  for (int j = 0; j < 24; j++) { yv[j] = ws[OFS_YV + n*24 + j]; yvo[j] = ws[OFS_YVO + n*24 + j]; }

  float hv = h_arr[layer];
  float dt = fminf(fmaxf(hv*hv, 1e-4f), 0.1f);
  float mxv = mix_arr[layer];
  float m = fminf(mxv*mxv, 1.f);

#pragma unroll
  for (int o = 0; o < MS; o++) {
    float g = cs_out[o] * sigmoidf_(cs_out[o]);
    float si = 0.f;
#pragma unroll
    for (int i2 = 0; i2 < MS; i2++) si += ys[i2] * si_s[i2*16 + o];
    si *= 0.25f;
    float dsv = m * g + (1.f - m) * si;
    float ysn = 2.f*ys[o] - yso[o] + dt * dsv;
    ws[OFS_YSO + n*MS + o] = ys[o];
    ws[OFS_YS  + n*MS + o] = ysn;
  }
  float yvn[24];
#pragma unroll
  for (int o = 0; o < MV; o++) {
    float gate = sigmoidf_(cs_out[MS + o]);
#pragma unroll
    for (int d = 0; d < 3; d++) {
      float si = 0.f;
#pragma unroll
      for (int i2 = 0; i2 < MV; i2++) si += yv[i2*3 + d] * si_v[i2*8 + o];
      si *= INV_SQRT8;
      float dv = m * gate * cv_out[o*3 + d] + (1.f - m) * si;
      float v = 2.f*yv[o*3 + d] - yvo[o*3 + d] + dt * dv;
      yvn[o*3 + d] = v;
      ws[OFS_YVO + n*24 + o*3 + d] = yv[o*3 + d];
      ws[OFS_YV  + n*24 + o*3 + d] = v;
    }
  }
#pragma unroll
  for (int c = 0; c < 2; c++)
#pragma unroll
    for (int d = 0; d < 3; d++) {
      float acc = 0.f;
#pragma unroll
      for (int k = 0; k < MV; k++) acc += yvn[k*3 + d] * K[c*8 + k];
      ws[OFS_X + n*6 + c*3 + d] = acc;
    }
}

// ---- finalize: copy x to d_out + tail scalars ----
__global__ void __launch_bounds__(256) k_final(const float* __restrict__ ws,
                                               float* __restrict__ out) {
  int i = blockIdx.x * blockDim.x + threadIdx.x;
  if (i < N_NODES*6) out[i] = ws[OFS_X + i];
  if (i == 0) { out[N_NODES*6] = -1.f; out[N_NODES*6 + 1] = -1.f; out[N_NODES*6 + 2] = 0.f; }
}

extern "C" void kernel_launch(void* const* d_in, const int* in_sizes, int n_in,
                              void* d_out, int out_size, void* d_ws, size_t ws_size,
                              hipStream_t stream) {
  const float* x_in  = (const float*)d_in[0];
  const int*   attr  = (const int*)  d_in[2];
  const int*   esrc  = (const int*)  d_in[3];
  const int*   edst  = (const int*)  d_in[4];
  const float* emb   = (const float*)d_in[5];
  const float* Kp    = (const float*)d_in[6];
  const float* hp    = (const float*)d_in[7];
  const float* mixp  = (const float*)d_in[8];
  const float* sc_s  = (const float*)d_in[9];
  const float* sc_v  = (const float*)d_in[10];
  const float* l1s   = (const float*)d_in[11];
  const float* l1v   = (const float*)d_in[12];
  const float* w1    = (const float*)d_in[13];
  const float* w2    = (const float*)d_in[14];
  const float* l2s   = (const float*)d_in[15];
  const float* l2v   = (const float*)d_in[16];
  const float* si_s  = (const float*)d_in[17];
  const float* si_v  = (const float*)d_in[18];

  float* ws = (float*)d_ws;
  int* ctr    = (int*)(ws + IOF_CTR);
  int* deg    = (int*)(ws + IOF_DEG);
  int* off    = (int*)(ws + IOF_OFF);
  int* cur    = (int*)(ws + IOF_CUR);
  int* eorder = (int*)(ws + IOF_EORD);
  int* act    = (int*)(ws + IOF_ACT);
  float* out = (float*)d_out;

  k_init<<<(N_NODES + 255)/256, 256, 0, stream>>>(x_in, Kp, ws);
  for (int i = 0; i < 2; i++) {
    k_attr<<<20, 256, 0, stream>>>(emb,
        sc_s + (size_t)i*MS*ED*CS, sc_v + (size_t)i*MV*ED*MV,
        l1s + (size_t)i*MS*ED*MS, l1v + (size_t)i*MV*ED*MV,
        l2s + (size_t)i*CS*ED*CS, l2v + (size_t)i*MV*ED*MV, ws, ctr, deg);
    k_node_pre<<<(N_NODES + 255)/256, 256, 0, stream>>>(attr, ws);
    k_compact<<<(N_EDGES + 255)/256, 256, 0, stream>>>(esrc, edst, ws, ctr, act, deg);
    k_scan<<<1, 256, 0, stream>>>(deg, off, cur);
    k_scatter<<<(N_EDGES + 255)/256, 256, 0, stream>>>(act, edst, ctr, cur, eorder);
    if (i == 0) {
      k_edge6<false><<<(N_EDGES + 63)/64, 256, 0, stream>>>(esrc, edst,
          w1 + (size_t)i*2*NBASIS*RH, w2 + (size_t)i*RH*640, ws, ctr, act);
      k_gather<false><<<(N_NODES*24 + 255)/256, 256, 0, stream>>>(off, deg, eorder, ws);
    } else {
      k_edge6<true><<<(N_EDGES + 63)/64, 256, 0, stream>>>(esrc, edst,
          w1 + (size_t)i*2*NBASIS*RH, w2 + (size_t)i*RH*640, ws, ctr, act);
      k_gather<true><<<(N_NODES*48 + 255)/256, 256, 0, stream>>>(off, deg, eorder, ws);
    }
    k_node_post<<<(N_NODES + 255)/256, 256, 0, stream>>>(attr,
        si_s + (size_t)i*MS*MS, si_v + (size_t)i*MV*MV, Kp, hp, mixp, i, ws);
  }
  k_final<<<(N_NODES*6 + 2 + 255)/256, 256, 0, stream>>>(ws, out);
}